// Round 1
// baseline (139.768 us; speedup 1.0000x reference)
//
#include <hip/hip_runtime.h>
#include <hip/hip_fp16.h>

// Scaled dot-product attention, N=8192, DK=DV=64, additive (+1.0) strict-upper mask.
// Strategy: f16 MFMA (32x32x16), swapped QK^T -> S^T so softmax state is lane-local,
// O computed transposed (O^T = V^T * P^T) so rescale/normalize is lane-local too.
// KV-split=8 for occupancy; partials combined in a second kernel.

#define NN    8192
#define DKK   64
#define QW    32              // q rows per wave (one 32x32 MFMA M-tile)
#define KVT   32              // kv rows per inner tile
#define SPLIT 8
#define KV_PER (NN / SPLIT)   // 1024 kv per block
#define NQT   (NN / QW)       // 256 q tiles
#define LOG2E 1.44269504088896340736f

typedef _Float16 f16x8 __attribute__((ext_vector_type(8)));
typedef float    f32x16 __attribute__((ext_vector_type(16)));
typedef float    f32x4  __attribute__((ext_vector_type(4)));

static __device__ __forceinline__ unsigned pk2(float a, float b) {
  // one u32 holding (f16(a) lo, f16(b) hi), RTZ
  return __builtin_bit_cast(unsigned, __builtin_amdgcn_cvt_pkrtz(a, b));
}

// ---- pass 1: fp32 -> f16; Q pre-scaled by (1/sqrt(64))*log2(e); V transposed ----
__global__ __launch_bounds__(256) void convert_kernel(
    const float* __restrict__ q, const float* __restrict__ k, const float* __restrict__ v,
    _Float16* __restrict__ qh, _Float16* __restrict__ kh, _Float16* __restrict__ vT) {
  int i = blockIdx.x * 256 + threadIdx.x;            // 0 .. N*64-1
  qh[i] = (_Float16)(q[i] * (0.125f * LOG2E));
  kh[i] = (_Float16)k[i];
  int kv = i >> 6, dv = i & 63;
  vT[(size_t)dv * NN + kv] = (_Float16)v[i];
}

// ---- pass 2: per-(q-tile, kv-split) flash attention partial ----
// Layouts (mfma_f32_32x32x16_f16, lane l, h = l>>5):
//   A-frag: A[i][k], i = l&31, k = 8h+e (e=0..7)      -> row-major 16B load
//   B-frag: B[k][j], j = l&31, k = 8h+e
//   D     : D[row][col], col = l&31, row = (r&3)+8*(r>>2)+4h   (r=0..15; m74/m101-verified)
// S^T = mfma(A=K, B=Q^T): lane holds S^T[kv=(r&3)+8*(r>>2)+4h][q=l&31]  -> q lane-local.
// O^T = mfma(A=V^T, B=P^T): B-frag needs P[q=l&31][kv=16s+8h+e]; lane holds P at
// kv = (r&3)+8*(r>>2)+4h, i.e. quads t: kv 8t+4h+{0..3}. Slice s uses quads 2s,2s+1
// with a half-wave exchange (shfl_xor 32) -- worked out in the loop below.
__global__ __launch_bounds__(64) void attn_partial(
    const _Float16* __restrict__ qh, const _Float16* __restrict__ kh,
    const _Float16* __restrict__ vT, float* __restrict__ Opart,
    float* __restrict__ Mpart, float* __restrict__ Lpart) {
  const int wid  = blockIdx.x;
  const int sp   = wid & (SPLIT - 1);
  const int qt   = wid / SPLIT;
  const int lane = threadIdx.x;
  const int ql   = lane & 31;
  const int h    = lane >> 5;
  const int qg   = qt * QW + ql;
  const int kv0  = sp * KV_PER;

  // Q fragments (B-operand of QK^T): Q[ql][16s + 8h + e], s=0..3
  f16x8 qf[4];
#pragma unroll
  for (int s = 0; s < 4; ++s)
    qf[s] = *(const f16x8*)(qh + (size_t)qg * DKK + s * 16 + h * 8);

  f32x16 acc0 = {}, acc1 = {};       // O^T[dv = dvt*32 + crow][q = ql]
  float m = -1e30f, l = 0.f;         // softmax state in exp2 domain, per q-row = ql

  for (int t = 0; t < KV_PER / KVT; ++t) {
    const int kvb = kv0 + t * KVT;

    // K fragments (A-operand): K[kvb+ql][16s + 8h + e]
    f16x8 kf[4];
#pragma unroll
    for (int s = 0; s < 4; ++s)
      kf[s] = *(const f16x8*)(kh + (size_t)(kvb + ql) * DKK + s * 16 + h * 8);
    // V^T fragments (A-operand of PV): vT[dvt*32+ql][kvb + 16s + 8h + e]
    f16x8 vf[4];
#pragma unroll
    for (int dvt = 0; dvt < 2; ++dvt)
#pragma unroll
      for (int s = 0; s < 2; ++s)
        vf[dvt * 2 + s] = *(const f16x8*)(vT + (size_t)(dvt * 32 + ql) * NN + kvb + s * 16 + h * 8);

    // S^T tile (already * log2e via Q prescale)
    f32x16 st = {};
#pragma unroll
    for (int s = 0; s < 4; ++s)
      st = __builtin_amdgcn_mfma_f32_32x32x16_f16(kf[s], qf[s], st, 0, 0, 0);

    // additive mask: +1.0 (nat) == +log2e (exp2 domain) where kv > q.
    // kvb and qt*32 are both multiples of 32 -> only three uniform cases.
    const int qrow0 = qt * QW;
    if (kvb > qrow0) {
#pragma unroll
      for (int r = 0; r < 16; ++r) st[r] += LOG2E;
    } else if (kvb == qrow0) {       // diagonal tile: kv_local > q_local
#pragma unroll
      for (int r = 0; r < 16; ++r) {
        const int kvl = (r & 3) + 8 * (r >> 2) + 4 * h;
        if (kvl > ql) st[r] += LOG2E;
      }
    }

    // online softmax (row = ql, halves of the 32 kv live in lanes l and l^32)
    float tm = st[0];
#pragma unroll
    for (int r = 1; r < 16; ++r) tm = fmaxf(tm, st[r]);
    tm = fmaxf(tm, __shfl_xor(tm, 32));
    const float mnew  = fmaxf(m, tm);
    const float alpha = __builtin_amdgcn_exp2f(m - mnew);
    float p[16];
    float rs = 0.f;
#pragma unroll
    for (int r = 0; r < 16; ++r) { p[r] = __builtin_amdgcn_exp2f(st[r] - mnew); rs += p[r]; }
    rs += __shfl_xor(rs, 32);
    l = l * alpha + rs;
    m = mnew;
#pragma unroll
    for (int r = 0; r < 16; ++r) { acc0[r] *= alpha; acc1[r] *= alpha; }

    // pack P quads: W[tq][0] = f16(p[4tq],p[4tq+1]) -> kv (8tq+4h, +1); W[tq][1] -> (+2,+3)
    unsigned W[4][2];
#pragma unroll
    for (int tq = 0; tq < 4; ++tq) {
      W[tq][0] = pk2(p[4 * tq + 0], p[4 * tq + 1]);
      W[tq][1] = pk2(p[4 * tq + 2], p[4 * tq + 3]);
    }

    // Build P^T B-frags per 16-kv slice s and do the two PV MFMAs.
    // h=0 needs kv {16s..16s+7} = own W[2s][*] ++ partner(h=1) W[2s][*]
    // h=1 needs kv {16s+8..16s+15} = partner(h=0) W[2s+1][*] ++ own W[2s+1][*]
#pragma unroll
    for (int s = 0; s < 2; ++s) {
      const unsigned X0 = W[2 * s][0], X1 = W[2 * s][1];
      const unsigned Y0 = W[2 * s + 1][0], Y1 = W[2 * s + 1][1];
      const unsigned sX0 = __shfl_xor(X0, 32), sX1 = __shfl_xor(X1, 32);
      const unsigned sY0 = __shfl_xor(Y0, 32), sY1 = __shfl_xor(Y1, 32);
      union { unsigned u[4]; f16x8 f; } pb;
      pb.u[0] = h ? sY0 : X0;
      pb.u[1] = h ? sY1 : X1;
      pb.u[2] = h ? Y0 : sX0;
      pb.u[3] = h ? Y1 : sX1;
      acc0 = __builtin_amdgcn_mfma_f32_32x32x16_f16(vf[0 * 2 + s], pb.f, acc0, 0, 0, 0);
      acc1 = __builtin_amdgcn_mfma_f32_32x32x16_f16(vf[1 * 2 + s], pb.f, acc1, 0, 0, 0);
    }
  }

  // partial epilogue: lane holds O^T[dv = dvt*32 + (r&3)+8*(r>>2)+4h][q = ql]
  float* Ob = Opart + ((size_t)sp * NN + qg) * 64;
#pragma unroll
  for (int tq = 0; tq < 4; ++tq) {
    f32x4 o0, o1;
#pragma unroll
    for (int j = 0; j < 4; ++j) { o0[j] = acc0[4 * tq + j]; o1[j] = acc1[4 * tq + j]; }
    *(f32x4*)(Ob + 8 * tq + 4 * h)      = o0;
    *(f32x4*)(Ob + 32 + 8 * tq + 4 * h) = o1;
  }
  if (h == 0) {
    Mpart[(size_t)sp * NN + qg] = m;
    Lpart[(size_t)sp * NN + qg] = l;
  }
}

// ---- pass 3: combine the SPLIT partials ----
__global__ __launch_bounds__(64) void combine_kernel(
    const float* __restrict__ Opart, const float* __restrict__ Mpart,
    const float* __restrict__ Lpart, float* __restrict__ out) {
  const int q  = blockIdx.x;
  const int dv = threadIdx.x;
  float ms[SPLIT];
  float M = -1e30f;
#pragma unroll
  for (int sp = 0; sp < SPLIT; ++sp) {
    ms[sp] = Mpart[(size_t)sp * NN + q];
    M = fmaxf(M, ms[sp]);
  }
  float L = 0.f, o = 0.f;
#pragma unroll
  for (int sp = 0; sp < SPLIT; ++sp) {
    const float w = __builtin_amdgcn_exp2f(ms[sp] - M);
    L += Lpart[(size_t)sp * NN + q] * w;
    o += Opart[((size_t)sp * NN + q) * 64 + dv] * w;
  }
  out[(size_t)q * 64 + dv] = o / L;
}

extern "C" void kernel_launch(void* const* d_in, const int* in_sizes, int n_in,
                              void* d_out, int out_size, void* d_ws, size_t ws_size,
                              hipStream_t stream) {
  const float* q = (const float*)d_in[0];
  const float* k = (const float*)d_in[1];
  const float* v = (const float*)d_in[2];
  float* out = (float*)d_out;

  char* ws = (char*)d_ws;
  const size_t half_sz = (size_t)NN * DKK * sizeof(_Float16);  // 1 MiB
  _Float16* qh = (_Float16*)(ws);
  _Float16* kh = (_Float16*)(ws + half_sz);
  _Float16* vT = (_Float16*)(ws + 2 * half_sz);
  float* Opart = (float*)(ws + 3 * half_sz);                       // SPLIT*N*64 f32 = 16 MiB
  float* Mpart = (float*)(ws + 3 * half_sz + (size_t)SPLIT * NN * 64 * 4);
  float* Lpart = (float*)(ws + 3 * half_sz + (size_t)SPLIT * NN * 64 * 4 + (size_t)SPLIT * NN * 4);

  convert_kernel<<<(NN * DKK) / 256, 256, 0, stream>>>(q, k, v, qh, kh, vT);
  attn_partial<<<NQT * SPLIT, 64, 0, stream>>>(qh, kh, vT, Opart, Mpart, Lpart);
  combine_kernel<<<NN, 64, 0, stream>>>(Opart, Mpart, Lpart, out);
}